// Round 16
// baseline (72.973 us; speedup 1.0000x reference)
//
#include <hip/hip_runtime.h>

// Decoder: 2-layer LSTM (H=32) + MLP (96), B=16384, 25 steps.
// R16 = R15 trims + Wcomb 2-phase recurrence + sigma-contiguous b64 state writes.
//  - Wcomb = Wih0@Wmlp (prep->d_ws): x never materializes. Per step:
//    PhaseA {GEMM1+act1} B | PhaseB {MLP off-chain, GEMM0(t+1)+act0} B.
//  - sigma(u)=swap(i,q) bit-fields (involution): thread's 4 acts store as ONE
//    ds_write_b64; all weight frags' K-columns pre-permuted by sigma.
//  - h0 read once in PhaseA, reused in registers in PhaseB.
//  - R15 carryovers: no h1lo, parity-buffered h0/h1 in one hh buffer,
//    lgkm-only barriers, exp2-prescale, native bf16 cvt, f32 I/O.

#define PRED 25
#define BATCH 16384
#define ET    32    // 2 streams x 16
#define HROW  128   // hh row (u16): 0..31 h0_A | 32..63 h0_B | 64..95 h1_A | 96..127 h1_B

typedef unsigned short u16;
typedef unsigned int   u32;
typedef unsigned long long u64;
typedef __attribute__((ext_vector_type(8))) short bf16x8;
typedef __attribute__((ext_vector_type(4))) float f32x4;

#define LOG2E  1.44269504088896340736f
#define LOG2E2 2.88539008177792681472f

#define BARRIER_NOVM() asm volatile("s_waitcnt lgkmcnt(0)\ns_barrier" ::: "memory")

__device__ __forceinline__ float rcp_(float x){ return __builtin_amdgcn_rcpf(x); }
__device__ __forceinline__ float ex2(float x){ return __builtin_amdgcn_exp2f(x); }
__device__ __forceinline__ float sigm2(float xp){ return rcp_(1.0f + ex2(-xp)); }
__device__ __forceinline__ float tanh2(float xp){ return 1.0f - 2.0f*rcp_(ex2(xp) + 1.0f); }

__device__ __forceinline__ u16 f2b(float f){
  __bf16 b = (__bf16)f;
  return __builtin_bit_cast(u16, b);
}
__device__ __forceinline__ u32 f2b2(float lo, float hi){
  return (u32)f2b(lo) | ((u32)f2b(hi) << 16);
}

// sigma: u = 16m+4i+q <-> v = 16m+4q+i  (involution; swaps two 2-bit fields)
__device__ __forceinline__ int sperm(int v){
  return (v & ~15) | ((v & 3) << 2) | ((v >> 2) & 3);
}

struct __align__(16) SM {
  u16 hh[2][16*HROW];
};
__device__ __forceinline__ int swh(int e, int k){ return e*HROW + (k ^ ((e&7)<<3)); }

// pack 8 weight cols for B read at storage positions kq*8+j -> source col sigma^-1
__device__ __forceinline__ bf16x8 pack8p(const float* row32, int kq, float s){
  union { bf16x8 v; u16 h[8]; } fr;
  #pragma unroll
  for (int j = 0; j < 8; ++j) fr.h[j] = f2b(row32[sperm(kq*8 + j)]*s);
  return fr.v;
}

// ---------- prep: ws[0..4095] = Wcomb = Wih0 @ Wmlp ; ws[4096..4223] = bcomb ----------
extern "C" __global__ void prep_kernel(const float* __restrict__ Wih0,
                                       const float* __restrict__ Wmlp,
                                       const float* __restrict__ bih0,
                                       const float* __restrict__ bhh0,
                                       const float* __restrict__ bmlp,
                                       float* __restrict__ ws){
  int idx = blockIdx.x*256 + threadIdx.x;
  if (idx < 4096){
    int g = idx >> 5, u = idx & 31;
    const float* wr = Wih0 + g*96;
    const float* wc = Wmlp + u;
    float a = 0.f;
    #pragma unroll 8
    for (int p = 0; p < 96; ++p) a = fmaf(wr[p], wc[p*32], a);
    ws[idx] = a;
  } else if (idx < 4224){
    int g = idx - 4096;
    const float* wr = Wih0 + g*96;
    float a = bih0[g] + bhh0[g];
    #pragma unroll 8
    for (int p = 0; p < 96; ++p) a = fmaf(wr[p], bmlp[p], a);
    ws[idx] = a;
  }
}

extern "C" __global__ __launch_bounds__(128, 1)
void decoder_kernel(const float* __restrict__ obs,  const float* __restrict__ lat,
                    const float* __restrict__ Wfc,  const float* __restrict__ bfc,
                    const float* __restrict__ Wih0, const float* __restrict__ Whh0,
                    const float* __restrict__ bih0, const float* __restrict__ bhh0,
                    const float* __restrict__ Wih1, const float* __restrict__ Whh1,
                    const float* __restrict__ bih1, const float* __restrict__ bhh1,
                    const float* __restrict__ Wmlp, const float* __restrict__ bmlp,
                    const float* __restrict__ ws,   float* __restrict__ out)
{
  __shared__ SM sm;
  const int tid = threadIdx.x;
  const int ebase = blockIdx.x * ET;
  const int mh = tid >> 6;        // wave 0..1 = m-half
  const int l  = tid & 63;
  const int lr = l & 15;          // frag row / e within stream
  const int kq = l >> 4;          // k-quad 0..3

  // ---- one-time init: h_init -> h0 parity1 + h1 parity0, sigma layout ----
  {
    int u = tid & 31, e8 = (tid >> 5)*8;
    const float* wf = Wfc + u*16;
    float bb = bfc[u];
    int sp = sperm(u);
    #pragma unroll
    for (int r = 0; r < 8; ++r){
      int e = e8 + r, s = e >> 4, er = e & 15;
      const float* lp = lat + (size_t)(ebase + e)*16;
      float a = bb;
      #pragma unroll
      for (int j = 0; j < 16; ++j) a = fmaf(wf[j], lp[j], a);
      u16 hb = f2b(a);
      sm.hh[s][swh(er, 32 + sp)] = hb;   // h0 region parity 1 (peel input)
      sm.hh[s][swh(er, 64 + sp)] = hb;   // h1 region parity 0 (= h1(-1))
    }
  }

  // ---- persistent weight frags (sigma-K, gate-permuted M, exp2-prescaled) ----
  bf16x8 wcombf[4], whh0f[4], wih1f[4], whh1f[4];
  #pragma unroll
  for (int i = 0; i < 4; ++i){
    int vg = (mh*4 + i)*16 + lr;
    int g  = (vg & 3)*32 + (vg >> 2);
    float sc = ((vg & 3) == 2) ? LOG2E2 : LOG2E;
    wcombf[i] = pack8p(ws   + g*32, kq, sc);
    whh0f[i]  = pack8p(Whh0 + g*32, kq, sc);
    wih1f[i]  = pack8p(Wih1 + g*32, kq, sc);
    whh1f[i]  = pack8p(Whh1 + g*32, kq, sc);
  }
  bf16x8 awm[3];
  #pragma unroll
  for (int i = 0; i < 3; ++i){
    int o = (mh*3 + i)*16 + lr;
    awm[i] = pack8p(Wmlp + o*32, kq, 1.0f);
  }
  // ---- register biases ----
  f32x4 bcombr[4], b1r[4];
  #pragma unroll
  for (int i = 0; i < 4; ++i){
    int u = (mh*4 + i)*4 + kq;
    #pragma unroll
    for (int r = 0; r < 4; ++r){
      int g = r*32 + u;
      float sc = (r == 2) ? LOG2E2 : LOG2E;
      bcombr[i][r] = ws[4096 + g]*sc;
      b1r[i][r]    = (bih1[g] + bhh1[g])*sc;
    }
  }
  f32x4 biasmv[3];
  #pragma unroll
  for (int i = 0; i < 3; ++i){
    int o0 = (mh*3 + i)*16 + kq*4;
    #pragma unroll
    for (int r = 0; r < 4; ++r) biasmv[i][r] = bmlp[o0 + r];
  }

  float c0s[2][4] = {{0,0,0,0},{0,0,0,0}};
  float c1s[2][4] = {{0,0,0,0},{0,0,0,0}};

  __syncthreads();   // init visible

  // ---- peel: GEMM0(0) = Wih0.x0 (natural K) + Whh0.h_init + b00 -> h0(0)@par0 ----
  {
    bf16x8 bhi[2], bx[2][3];
    #pragma unroll
    for (int s = 0; s < 2; ++s){
      bhi[s] = *(const bf16x8*)&sm.hh[s][swh(lr, 32 + kq*8)];
      const float* xr = obs + ((size_t)15*BATCH + ebase + 16*s + lr)*96;
      #pragma unroll
      for (int c = 0; c < 3; ++c){
        union{bf16x8 v; u16 q[8];} fr;
        const float* s8 = xr + c*32 + kq*8;
        #pragma unroll
        for (int j = 0; j < 8; ++j) fr.q[j] = f2b(s8[j]);
        bx[s][c] = fr.v;
      }
    }
    #pragma unroll
    for (int i = 0; i < 4; ++i){
      int vg = (mh*4 + i)*16 + lr;
      int g  = (vg & 3)*32 + (vg >> 2);
      float sc = ((vg & 3) == 2) ? LOG2E2 : LOG2E;
      bf16x8 wf[3];
      #pragma unroll
      for (int c = 0; c < 3; ++c){
        union{bf16x8 v; u16 q[8];} fr;
        const float* s8 = Wih0 + g*96 + c*32 + kq*8;
        #pragma unroll
        for (int j = 0; j < 8; ++j) fr.q[j] = f2b(s8[j]*sc);
        wf[c] = fr.v;
      }
      int u = (mh*4 + i)*4 + kq;
      f32x4 b00;
      #pragma unroll
      for (int r = 0; r < 4; ++r){
        int gg = r*32 + u;
        b00[r] = (bih0[gg] + bhh0[gg])*((r == 2) ? LOG2E2 : LOG2E);
      }
      #pragma unroll
      for (int s = 0; s < 2; ++s){
        f32x4 acc = b00;
        acc = __builtin_amdgcn_mfma_f32_16x16x32_bf16(wf[0], bx[s][0], acc, 0, 0, 0);
        acc = __builtin_amdgcn_mfma_f32_16x16x32_bf16(wf[1], bx[s][1], acc, 0, 0, 0);
        acc = __builtin_amdgcn_mfma_f32_16x16x32_bf16(wf[2], bx[s][2], acc, 0, 0, 0);
        acc = __builtin_amdgcn_mfma_f32_16x16x32_bf16(whh0f[i], bhi[s], acc, 0, 0, 0);
        float ig = sigm2(acc[0]);
        float fg = sigm2(acc[1]);
        float gg = tanh2(acc[2]);
        float og = sigm2(acc[3]);
        float cn = fmaf(fg, c0s[s][i], ig*gg);
        c0s[s][i] = cn;
        // scalar write ok in peel (one-time); position sigma(u)=16mh+4kq+i
        sm.hh[s][swh(lr, 16*mh + 4*kq + i)] = f2b(og * tanh2(cn*LOG2E2));
      }
    }
  }
  BARRIER_NOVM();   // h0(0) visible

  f32x4 am[2][3];

  for (int t = 0; t < PRED; ++t){
    const int p  = t & 1;
    const int pn = p ^ 1;
    // ---- Phase A: GEMM1(t) = Wih1.h0(t) + Whh1.h1(t-1) ----
    bf16x8 bh0[2], bh1p[2];
    #pragma unroll
    for (int s = 0; s < 2; ++s){
      bh0[s]  = *(const bf16x8*)&sm.hh[s][swh(lr, 32*p + kq*8)];        // h0(t)
      bh1p[s] = *(const bf16x8*)&sm.hh[s][swh(lr, 64 + 32*p + kq*8)];   // h1(t-1)
    }
    #pragma unroll
    for (int s = 0; s < 2; ++s){
      float hv[4];
      #pragma unroll
      for (int i = 0; i < 4; ++i){
        f32x4 a = b1r[i];
        a = __builtin_amdgcn_mfma_f32_16x16x32_bf16(wih1f[i], bh0[s],  a, 0, 0, 0);
        a = __builtin_amdgcn_mfma_f32_16x16x32_bf16(whh1f[i], bh1p[s], a, 0, 0, 0);
        float ig = sigm2(a[0]);
        float fg = sigm2(a[1]);
        float gg = tanh2(a[2]);
        float og = sigm2(a[3]);
        float cn = fmaf(fg, c1s[s][i], ig*gg);
        c1s[s][i] = cn;
        hv[i] = og * tanh2(cn*LOG2E2);
      }
      u64 pk = (u64)f2b2(hv[0], hv[1]) | ((u64)f2b2(hv[2], hv[3]) << 32);
      *(u64*)&sm.hh[s][swh(lr, 64 + 32*pn + 16*mh + 4*kq)] = pk;  // h1(t)
    }
    BARRIER_NOVM();   // h1(t) visible
    // ---- Phase B: MLP (off-chain) + GEMM0(t+1) (on-chain; h0 reused from regs) ----
    bf16x8 bh1n[2];
    #pragma unroll
    for (int s = 0; s < 2; ++s)
      bh1n[s] = *(const bf16x8*)&sm.hh[s][swh(lr, 64 + 32*pn + kq*8)];  // h1(t)
    #pragma unroll
    for (int s = 0; s < 2; ++s)
      #pragma unroll
      for (int i = 0; i < 3; ++i){
        f32x4 a = biasmv[i];
        a = __builtin_amdgcn_mfma_f32_16x16x32_bf16(awm[i], bh1n[s], a, 0, 0, 0);
        am[s][i] = a;
      }
    if (t < PRED-1){
      #pragma unroll
      for (int s = 0; s < 2; ++s){
        float hv[4];
        #pragma unroll
        for (int i = 0; i < 4; ++i){
          f32x4 a = bcombr[i];
          a = __builtin_amdgcn_mfma_f32_16x16x32_bf16(wcombf[i], bh1n[s], a, 0, 0, 0);
          a = __builtin_amdgcn_mfma_f32_16x16x32_bf16(whh0f[i],  bh0[s],  a, 0, 0, 0);
          float ig = sigm2(a[0]);
          float fg = sigm2(a[1]);
          float gg = tanh2(a[2]);
          float og = sigm2(a[3]);
          float cn = fmaf(fg, c0s[s][i], ig*gg);
          c0s[s][i] = cn;
          hv[i] = og * tanh2(cn*LOG2E2);
        }
        u64 pk = (u64)f2b2(hv[0], hv[1]) | ((u64)f2b2(hv[2], hv[3]) << 32);
        *(u64*)&sm.hh[s][swh(lr, 32*pn + 16*mh + 4*kq)] = pk;  // h0(t+1)
      }
    }
    BARRIER_NOVM();   // h0(t+1) visible
    // ---- global stores AFTER barrier: never drained in-loop ----
    #pragma unroll
    for (int s = 0; s < 2; ++s){
      float* outb = out + (size_t)t*BATCH*96 + (size_t)(ebase + s*16 + lr)*96;
      #pragma unroll
      for (int i = 0; i < 3; ++i){
        int o0 = (mh*3 + i)*16 + kq*4;
        *(f32x4*)(outb + o0) = am[s][i];
      }
    }
  }
}

extern "C" void kernel_launch(void* const* d_in, const int* in_sizes, int n_in,
                              void* d_out, int out_size, void* d_ws, size_t ws_size,
                              hipStream_t stream){
  const float* obs  = (const float*)d_in[0];
  const float* lat  = (const float*)d_in[1];
  const float* Wfc  = (const float*)d_in[3];
  const float* bfc  = (const float*)d_in[4];
  const float* Wih0 = (const float*)d_in[5];
  const float* Whh0 = (const float*)d_in[6];
  const float* bih0 = (const float*)d_in[7];
  const float* bhh0 = (const float*)d_in[8];
  const float* Wih1 = (const float*)d_in[9];
  const float* Whh1 = (const float*)d_in[10];
  const float* bih1 = (const float*)d_in[11];
  const float* bhh1 = (const float*)d_in[12];
  const float* Wmlp = (const float*)d_in[13];
  const float* bmlp = (const float*)d_in[14];
  float* ws = (float*)d_ws;

  prep_kernel<<<dim3(17), dim3(256), 0, stream>>>(Wih0, Wmlp, bih0, bhh0, bmlp, ws);
  decoder_kernel<<<dim3(BATCH/ET), dim3(128), 0, stream>>>(
      obs, lat, Wfc, bfc, Wih0, Whh0, bih0, bhh0,
      Wih1, Whh1, bih1, bhh1, Wmlp, bmlp, ws, (float*)d_out);
}